// Round 11
// baseline (263.553 us; speedup 1.0000x reference)
//
#include <hip/hip_runtime.h>
#include <math.h>

// ---------------------------------------------------------------------------
// Sparse_Attn_Logic — round 11.
// R10: 220.4us, launch surgery on tiny kernels was worth ~2us. Remaining
// structure cost: the FC sub-chain (final_ev -> gemm1 -> gemm2 -> gemm3+fc4)
// = 4 dispatches + 3 gaps + z0/z1/z2 HBM round-trips. Each stage only needs a
// 16-batch-row strip and feeds the next stage's K in full -> fuse ALL of it
// into one 64-block x 1024-thread kernel carrying the strip through LDS
// (~90KB; rows padded so b128 LDS reads stay >=2 lanes/bank). 16 waves/block
// keeps 4 waves/SIMD for MFMA latency hiding. Bit-identical arithmetic.
// Chain: leaf -> prep -> branches -> pstats -> megaFC  (5 dispatches).
// ---------------------------------------------------------------------------

#define L_MP 31

using s8v = __attribute__((ext_vector_type(8))) short;   // 8 bf16 = 4 VGPRs
using f4v = __attribute__((ext_vector_type(4))) float;   // MFMA acc

__device__ __forceinline__ ushort f2bf(float f) {        // RNE fp32->bf16
    unsigned u = __float_as_uint(f);
    u += 0x7fffu + ((u >> 16) & 1u);
    return (ushort)(u >> 16);
}
__device__ __forceinline__ float bf2f(ushort u) {
    return __uint_as_float(((unsigned)u) << 16);
}

// ---------------- K1: x-stats partials  ∪  weight transpose ---------------
__global__ __launch_bounds__(256) void leaf_kernel(
    const float* __restrict__ x, double* __restrict__ xp,
    const float* __restrict__ w1, const float* __restrict__ w2,
    const float* __restrict__ w3,
    ushort* __restrict__ wt1, ushort* __restrict__ wt2, ushort* __restrict__ wt3)
{
    __shared__ __align__(16) float xr[1040];
    __shared__ float wred[4][17];
    __shared__ float tile[32][33];
    int bx = blockIdx.x, tid = threadIdx.x;

    if (bx < 1024) {
        int b = bx;
        for (int i = tid; i < 1024; i += 256) xr[i] = x[b * 1024 + i];
        if (tid < 16) xr[1024 + tid] = 0.f;
        __syncthreads();
        float acc[17];
#pragma unroll
        for (int d = 0; d < 17; ++d) acc[d] = 0.f;
        for (int p = tid; p < 1024; p += 256) {
            float v = xr[p];
            acc[16] += v;
#pragma unroll
            for (int d = 0; d < 16; ++d)
                acc[d] += v * xr[p + d];
        }
#pragma unroll
        for (int off = 32; off >= 1; off >>= 1)
#pragma unroll
            for (int d = 0; d < 17; ++d)
                acc[d] += __shfl_down(acc[d], off);
        int wave = tid >> 6, lane = tid & 63;
        if (lane == 0)
            for (int d = 0; d < 17; ++d) wred[wave][d] = acc[d];
        __syncthreads();
        if (tid < 17) {
            double tot = (double)wred[0][tid] + (double)wred[1][tid]
                       + (double)wred[2][tid] + (double)wred[3][tid];
            xp[tid * 1024 + b] = tot;
        }
    } else {
        int t2 = bx - 1024;
        const float* W; ushort* Wt; int K, N, ntx, tl;
        if (t2 < 768)       { W = w1; Wt = wt1; K = 768;  N = 1024; ntx = 32; tl = t2; }
        else if (t2 < 1280) { W = w2; Wt = wt2; K = 1024; N = 512;  ntx = 16; tl = t2 - 768; }
        else                { W = w3; Wt = wt3; K = 512;  N = 128;  ntx = 4;  tl = t2 - 1280; }
        int n0 = (tl % ntx) * 32, k0 = (tl / ntx) * 32;
        int tx = tid & 31, ty = tid >> 5;
#pragma unroll
        for (int i = 0; i < 4; ++i)
            tile[ty + 8 * i][tx] = W[(size_t)(k0 + ty + 8 * i) * N + n0 + tx];
        __syncthreads();
#pragma unroll
        for (int i = 0; i < 4; ++i)
            Wt[(size_t)(n0 + ty + 8 * i) * K + k0 + tx] = f2bf(tile[tx][ty + 8 * i]);
    }
}

// ---------------- K2: reduce xp + filters + analytic BN1 ------------------
__global__ __launch_bounds__(512) void prep_kernel(
    const double* __restrict__ xp,
    const float* __restrict__ la_a, const float* __restrict__ la_b,
    const float* __restrict__ bn1_g, const float* __restrict__ bn1_b,
    float* __restrict__ g18_out, float* __restrict__ a1d1_out)
{
    __shared__ double stats[17];
    __shared__ float fs[32][16];
    int tid = threadIdx.x, wv = tid >> 6, lane = tid & 63;

    for (int row = wv; row < 17; row += 8) {
        const double* r = xp + (size_t)row * 1024;
        double a = 0.0;
        for (int i = lane; i < 1024; i += 64) a += r[i];
#pragma unroll
        for (int off = 32; off >= 1; off >>= 1) a += __shfl_down(a, off);
        if (lane == 0) stats[row] = a;
    }

    {
        int c = tid >> 4, k = tid & 15;
        const double A = 0.08, ep = 0.03, tal = 0.1;
        const double w = 2.0 * 3.14159265358979323846 * 50.0;
        const double q = 1.0 - ep * ep;
        double t = (double)k / 15.0;
        double p = t - (double)la_b[c] / (double)la_a[c];
        double arg = w * (p - tal);
        double y = A * exp(-ep / sqrt(q) * arg) * (-sin(arg));
        fs[c][k] = (float)y;
    }
    __syncthreads();
    if (tid < 32) {
        int c = tid;
        for (int i = 0; i < 18; ++i) {
            float g = 0.f;
            for (int k = i - 2; k <= i; ++k)
                if (k >= 0 && k < 16) g += fs[c][k];
            g18_out[c * 18 + i] = g;
        }
        double Sf = 0.0;
        for (int k = 0; k < 16; ++k) Sf += (double)fs[c][k];
        double E2 = 0.0;
        for (int k = 0; k < 16; ++k)
            for (int k2 = 0; k2 < 16; ++k2)
                E2 += (double)fs[c][k] * (double)fs[c][k2]
                    * stats[k > k2 ? k - k2 : k2 - k];
        const double N = 1024.0 * 1041.0;
        double Sx = stats[16];
        double mc  = Sx * Sf / N;
        double var = E2 / N - mc * mc;
        double invstd = 1.0 / sqrt(var + 1e-5);
        float alpha = bn1_g[c] * (float)invstd;
        a1d1_out[c]      = alpha / 3.0f;
        a1d1_out[32 + c] = bn1_b[c] - (float)mc * alpha;
    }
}

// ---------------- K3: fused conv+BN+pool + both branches ------------------
__global__ __launch_bounds__(256) void branches_kernel(
    const float* __restrict__ x,
    const float* __restrict__ g18g, const float* __restrict__ a1d1,
    const float* __restrict__ a1w_g, const float* __restrict__ a1b_g,
    const float* __restrict__ e1w_g, const float* __restrict__ e1b_g,
    const float* __restrict__ f1w_g, const float* __restrict__ f1b_g,
    const float* __restrict__ faw_g, const float* __restrict__ fab_g,
    float* __restrict__ p1, float* __restrict__ p2)
{
    __shared__ float xs[1140];            // swizzled x, P(i)=i+(i>>4)
    __shared__ float htail[16][6];

    int blk = blockIdx.x;
    int b = blk >> 1, hf = blk & 1;
    int t = threadIdx.x;
    int wv = t >> 6, lane = t & 63;

    {
        float4 v = ((const float4*)(x + (size_t)b * 1024))[t];
        int li = 16 + 4 * t;
        int ph = li + (li >> 4);
        xs[ph] = v.x; xs[ph + 1] = v.y; xs[ph + 2] = v.z; xs[ph + 3] = v.w;
        if (t < 16) xs[t] = 0.f;
        if (t < 32) { int i = 1040 + t; xs[i + (i >> 4)] = 0.f; }
    }
    __syncthreads();

    if (t < 96) {
        int cl = t / 6, e = t - 6 * (t / 6);
        int cg = hf * 16 + cl;
        float s = 0.f;
#pragma unroll
        for (int i = 0; i < 18; ++i) {
            int li = 1024 + 2 * e + i;
            s += g18g[cg * 18 + i] * xs[li + (li >> 4)];
        }
        htail[cl][e] = s * a1d1[cg] + a1d1[32 + cg];
    }
    __syncthreads();

    float xw[32];
    {
        int base = 17 * lane;
#pragma unroll
        for (int q = 0; q < 16; ++q) xw[q] = xs[base + q];
#pragma unroll
        for (int q = 0; q < 16; ++q) xw[16 + q] = xs[base + 17 + q];
    }

    for (int cc = 0; cc < 4; ++cc) {
        int cl = wv * 4 + cc;
        int cg = __builtin_amdgcn_readfirstlane(hf * 16 + cl);  // SGPR index
        float alpha = a1d1[cg], delta = a1d1[32 + cg];

        float hv[8];
        {
            float g[18];
#pragma unroll
            for (int i = 0; i < 18; ++i) g[i] = g18g[cg * 18 + i];
#pragma unroll
            for (int jj = 0; jj < 8; ++jj) {
                float s = 0.f;
#pragma unroll
                for (int i = 0; i < 18; ++i) s += g[i] * xw[2 * jj + i];
                hv[jj] = s * alpha + delta;
            }
        }

        float x1v[4], x2v[4];
        {
            float hx[14];
#pragma unroll
            for (int q = 0; q < 8; ++q) hx[q] = hv[q];
#pragma unroll
            for (int q = 0; q < 6; ++q) {
                float u = __shfl_down(hv[q], 1);
                float tl = htail[cl][q];
                hx[8 + q] = (lane == 63) ? tl : u;
            }
            float wa[8], wf[8];
            float A1 = a1b_g[cg], F1 = 1.f - f1b_g[cg];
#pragma unroll
            for (int k = 0; k < 8; ++k) {
                wa[k] = a1w_g[cg * 8 + k];
                wf[k] = f1w_g[cg * 8 + k];
                A1 -= wa[k];
            }
#pragma unroll
            for (int nn = 0; nn < 4; ++nn) {
                float s1 = A1, s2 = F1;
#pragma unroll
                for (int k = 0; k < 8; ++k) {
                    float h = hx[2 * nn + k];
                    s1 += h * wa[k];
                    s2 += h * wf[k];
                }
                x1v[nn] = s1 > 0.f ? s1 : 0.f;
                x2v[nn] = s2 > 0.f ? s2 : 0.f;
            }
        }

        float y1v[2], y2v[2];
        {
            float xx1[10], xx2[10];
#pragma unroll
            for (int q = 0; q < 4; ++q) { xx1[q] = x1v[q]; xx2[q] = x2v[q]; }
#pragma unroll
            for (int q = 0; q < 4; ++q) {
                xx1[4 + q] = __shfl_down(x1v[q], 1);
                xx2[4 + q] = __shfl_down(x2v[q], 1);
            }
#pragma unroll
            for (int q = 0; q < 2; ++q) {
                xx1[8 + q] = __shfl_down(x1v[q], 2);
                xx2[8 + q] = __shfl_down(x2v[q], 2);
            }
            float we[8], wfa[8];
            float E1 = 1.f - e1b_g[cg], FA = fab_g[cg];
#pragma unroll
            for (int k = 0; k < 8; ++k) {
                we[k]  = e1w_g[cg * 8 + k];
                wfa[k] = faw_g[cg * 8 + k];
                FA -= wfa[k];
            }
#pragma unroll
            for (int mm = 0; mm < 2; ++mm) {
                float s1 = E1, s2 = FA;
#pragma unroll
                for (int k = 0; k < 8; ++k) {
                    s1 += xx1[2 * mm + k] * we[k];
                    s2 += xx2[2 * mm + k] * wfa[k];
                }
                y1v[mm] = s1 > 0.f ? s1 : 0.f;
                y2v[mm] = s2 > 0.f ? s2 : 0.f;
            }
        }

        {
            float m1 = fmaxf(y1v[0], y1v[1]);
            float m2 = fmaxf(y2v[0], y2v[1]);
            float n1 = __shfl_down(m1, 1);
            float n2 = __shfl_down(m2, 1);
            int tt = lane >> 1;
            if (!(lane & 1) && tt < L_MP) {
                int bc = b * 32 + hf * 16 + cl;
                p1[(size_t)bc * L_MP + tt] = fmaxf(m1, n1);
                p2[(size_t)bc * L_MP + tt] = fmaxf(m2, n2);
            }
        }
    }
}

// ---------------- K3b: BN2/3 stats from p1/p2 (64 blocks) -----------------
__global__ __launch_bounds__(256) void pstats_kernel(
    const float* __restrict__ p1, const float* __restrict__ p2,
    double* __restrict__ bn_d)
{
    __shared__ double wr[4][2];
    int bx = blockIdx.x, arr = bx >> 5, c = bx & 31;
    const float* p = arr ? p2 : p1;
    int t = threadIdx.x, wv = t >> 6, lane = t & 63;
    double s = 0.0, q = 0.0;
    for (int bb = t; bb < 1024; bb += 256) {
        const float* r = p + ((size_t)bb * 32 + c) * L_MP;
#pragma unroll
        for (int j = 0; j < L_MP; ++j) {
            double v = (double)r[j];
            s += v; q += v * v;
        }
    }
#pragma unroll
    for (int off = 32; off >= 1; off >>= 1) {
        s += __shfl_down(s, off);
        q += __shfl_down(q, off);
    }
    if (lane == 0) { wr[wv][0] = s; wr[wv][1] = q; }
    __syncthreads();
    if (t == 0) {
        bn_d[arr * 64 + c]      = wr[0][0] + wr[1][0] + wr[2][0] + wr[3][0];
        bn_d[arr * 64 + 32 + c] = wr[0][1] + wr[1][1] + wr[2][1] + wr[3][1];
    }
}

// ---------------- K5: megaFC — final_ev + gemm1 + gemm2 + gemm3 + fc4 -----
// 64 blocks x 1024 thr (16 waves). Block blk owns batch rows blk*16..+15;
// the strip walks z0 -> z1 -> z2 -> z3 -> out entirely in LDS. Row pads
// (776/1032/520/136 ushorts) keep b128 LDS reads at the free 2-lanes/bank.
// All arithmetic chains bit-identical to the R10 separate kernels.
__global__ __launch_bounds__(1024) void megafc_kernel(
    const float* __restrict__ p1, const float* __restrict__ p2,
    const float* __restrict__ e2w_g, const float* __restrict__ e2b_g,
    const float* __restrict__ f2w_g, const float* __restrict__ f2b_g,
    const double* __restrict__ bn_d,
    const float* __restrict__ bn2_g, const float* __restrict__ bn2_b,
    const float* __restrict__ bn3_g, const float* __restrict__ bn3_b,
    const ushort* __restrict__ wt1, const float* __restrict__ b1,
    const ushort* __restrict__ wt2, const float* __restrict__ b2,
    const ushort* __restrict__ wt3, const float* __restrict__ b3,
    const float* __restrict__ w4, const float* __restrict__ b4,
    float* __restrict__ out)
{
    __shared__ __align__(16) ushort z0s[16][776];
    __shared__ __align__(16) ushort z1s[16][1032];
    __shared__ __align__(16) ushort z2s[16][520];
    __shared__ __align__(16) ushort z3s[16][136];
    __shared__ float pr[2][32][31];
    __shared__ float w2s[2][32][8];
    __shared__ float al[2][32], de[2][32], eb[2][32];

    int blk = blockIdx.x;
    int t = threadIdx.x;
    int wv = t >> 6, lane = t & 63;
    int r = lane & 15, q = lane >> 4;

    // ---- phase 0: constants ----
    if (t < 256) { w2s[0][0][t] = e2w_g[t]; w2s[1][0][t] = f2w_g[t]; }
    if (t >= 960) {                         // folded bn23_finalize
        int tt = t - 960;
        int br = tt >> 5, c = tt & 31;
        double sum = bn_d[br * 64 + c], sq = bn_d[br * 64 + 32 + c];
        const double N = 1024.0 * 31.0;
        double mean = sum / N;
        double var = sq / N - mean * mean;
        float g  = br ? bn3_g[c] : bn2_g[c];
        float be = br ? bn3_b[c] : bn2_b[c];
        float alpha = g * (float)(1.0 / sqrt(var + 1e-5));
        al[br][c] = alpha;
        de[br][c] = be - (float)mean * alpha;
        eb[br][c] = br ? f2b_g[c] : e2b_g[c];
    }
    __syncthreads();

    // ---- phase 1: z0 strip (16 rows x 768), identical math to final_ev ---
    for (int bb = 0; bb < 16; ++bb) {
        int gb = blk * 16 + bb;
        if (t < 992) {
            pr[0][0][t] = p1[(size_t)gb * 992 + t];
            pr[1][0][t] = p2[(size_t)gb * 992 + t];
        }
        __syncthreads();
        if (t < 768) {
            int u = t;
            int br = u / 384, rem = u - br * 384;
            int c = rem / 12, tt = rem - c * 12;
            float a = al[br][c], d = de[br][c];
            float s = 1.f - eb[br][c];
#pragma unroll
            for (int k = 0; k < 8; ++k)
                s += (pr[br][c][2 * tt + k] * a + d) * w2s[br][c][k];
            z0s[bb][u] = f2bf(s > 0.f ? s : 0.f);
        }
        __syncthreads();
    }

    // ---- phase 2: gemm1  z1 = relu(z0 @ wt1^T + b1)  (K=768, N=1024) -----
    // wave wv: N-tiles [wv*4, wv*4+4) as 2 NT=2 pairs.
#pragma unroll
    for (int pp = 0; pp < 2; ++pp) {
        int nt0 = wv * 4 + pp * 2;
        const ushort* bpa = wt1 + (size_t)(nt0 * 16 + r) * 768 + q * 8;
        const ushort* bpb = wt1 + (size_t)((nt0 + 1) * 16 + r) * 768 + q * 8;
        const ushort* apl = &z0s[r][q * 8];
        f4v ac0 = {0.f, 0.f, 0.f, 0.f}, ac1 = {0.f, 0.f, 0.f, 0.f};
        s8v a0 = *(const s8v*)apl;
        s8v c0 = *(const s8v*)bpa;
        s8v d0 = *(const s8v*)bpb;
#pragma unroll 4
        for (int i = 0; i < 24; ++i) {
            int j = (i + 1 < 24) ? i + 1 : i;
            s8v a1 = *(const s8v*)(apl + j * 32);
            s8v c1 = *(const s8v*)(bpa + (size_t)j * 32);
            s8v d1 = *(const s8v*)(bpb + (size_t)j * 32);
            ac0 = __builtin_amdgcn_mfma_f32_16x16x32_bf16(a0, c0, ac0, 0, 0, 0);
            ac1 = __builtin_amdgcn_mfma_f32_16x16x32_bf16(a0, d0, ac1, 0, 0, 0);
            a0 = a1; c0 = c1; d0 = d1;
        }
        float bv0 = b1[nt0 * 16 + r], bv1 = b1[(nt0 + 1) * 16 + r];
#pragma unroll
        for (int rr = 0; rr < 4; ++rr) {
            float v0 = ac0[rr] + bv0; v0 = v0 > 0.f ? v0 : 0.f;
            float v1 = ac1[rr] + bv1; v1 = v1 > 0.f ? v1 : 0.f;
            z1s[q * 4 + rr][nt0 * 16 + r]       = f2bf(v0);
            z1s[q * 4 + rr][(nt0 + 1) * 16 + r] = f2bf(v1);
        }
    }
    __syncthreads();

    // ---- phase 3: gemm2  z2 = relu(z1 @ wt2^T + b2)  (K=1024, N=512) -----
    {
        int nt0 = wv * 2;
        const ushort* bpa = wt2 + (size_t)(nt0 * 16 + r) * 1024 + q * 8;
        const ushort* bpb = wt2 + (size_t)((nt0 + 1) * 16 + r) * 1024 + q * 8;
        const ushort* apl = &z1s[r][q * 8];
        f4v ac0 = {0.f, 0.f, 0.f, 0.f}, ac1 = {0.f, 0.f, 0.f, 0.f};
        s8v a0 = *(const s8v*)apl;
        s8v c0 = *(const s8v*)bpa;
        s8v d0 = *(const s8v*)bpb;
#pragma unroll 4
        for (int i = 0; i < 32; ++i) {
            int j = (i + 1 < 32) ? i + 1 : i;
            s8v a1 = *(const s8v*)(apl + j * 32);
            s8v c1 = *(const s8v*)(bpa + (size_t)j * 32);
            s8v d1 = *(const s8v*)(bpb + (size_t)j * 32);
            ac0 = __builtin_amdgcn_mfma_f32_16x16x32_bf16(a0, c0, ac0, 0, 0, 0);
            ac1 = __builtin_amdgcn_mfma_f32_16x16x32_bf16(a0, d0, ac1, 0, 0, 0);
            a0 = a1; c0 = c1; d0 = d1;
        }
        float bv0 = b2[nt0 * 16 + r], bv1 = b2[(nt0 + 1) * 16 + r];
#pragma unroll
        for (int rr = 0; rr < 4; ++rr) {
            float v0 = ac0[rr] + bv0; v0 = v0 > 0.f ? v0 : 0.f;
            float v1 = ac1[rr] + bv1; v1 = v1 > 0.f ? v1 : 0.f;
            z2s[q * 4 + rr][nt0 * 16 + r]       = f2bf(v0);
            z2s[q * 4 + rr][(nt0 + 1) * 16 + r] = f2bf(v1);
        }
    }
    __syncthreads();

    // ---- phase 4: gemm3  z3 = relu(z2 @ wt3^T + b3)  (K=512, N=128) ------
    if (wv < 4) {
        int nt0 = wv * 2;
        const ushort* bpa = wt3 + (size_t)(nt0 * 16 + r) * 512 + q * 8;
        const ushort* bpb = wt3 + (size_t)((nt0 + 1) * 16 + r) * 512 + q * 8;
        const ushort* apl = &z2s[r][q * 8];
        f4v ac0 = {0.f, 0.f, 0.f, 0.f}, ac1 = {0.f, 0.f, 0.f, 0.f};
        s8v a0 = *(const s8v*)apl;
        s8v c0 = *(const s8v*)bpa;
        s8v d0 = *(const s8v*)bpb;
#pragma unroll 4
        for (int i = 0; i < 16; ++i) {
            int j = (i + 1 < 16) ? i + 1 : i;
            s8v a1 = *(const s8v*)(apl + j * 32);
            s8v c1 = *(const s8v*)(bpa + (size_t)j * 32);
            s8v d1 = *(const s8v*)(bpb + (size_t)j * 32);
            ac0 = __builtin_amdgcn_mfma_f32_16x16x32_bf16(a0, c0, ac0, 0, 0, 0);
            ac1 = __builtin_amdgcn_mfma_f32_16x16x32_bf16(a0, d0, ac1, 0, 0, 0);
            a0 = a1; c0 = c1; d0 = d1;
        }
        float bv0 = b3[nt0 * 16 + r], bv1 = b3[(nt0 + 1) * 16 + r];
#pragma unroll
        for (int rr = 0; rr < 4; ++rr) {
            float v0 = ac0[rr] + bv0; v0 = v0 > 0.f ? v0 : 0.f;
            float v1 = ac1[rr] + bv1; v1 = v1 > 0.f ? v1 : 0.f;
            z3s[q * 4 + rr][nt0 * 16 + r]       = f2bf(v0);
            z3s[q * 4 + rr][(nt0 + 1) * 16 + r] = f2bf(v1);
        }
    }
    __syncthreads();

    // ---- phase 5: fc4  out = relu(z3 @ w4 + b4)  (N=10) ------------------
    if (t < 160) {
        int m = t / 10, n = t - 10 * (t / 10);
        float a = b4[n];
#pragma unroll 8
        for (int k = 0; k < 128; ++k)
            a += bf2f(z3s[m][k]) * w4[k * 10 + n];
        out[(size_t)(blk * 16 + m) * 10 + n] = a > 0.f ? a : 0.f;
    }
}

// ---------------------------------------------------------------------------
extern "C" void kernel_launch(void* const* d_in, const int* in_sizes, int n_in,
                              void* d_out, int out_size, void* d_ws, size_t ws_size,
                              hipStream_t stream)
{
    (void)in_sizes; (void)n_in; (void)out_size; (void)ws_size;
    const float* x      = (const float*)d_in[0];
    const float* la_a   = (const float*)d_in[1];
    const float* la_b   = (const float*)d_in[2];
    const float* bn1_g  = (const float*)d_in[4];
    const float* bn1_b  = (const float*)d_in[5];
    const float* a1_w   = (const float*)d_in[6];
    const float* a1_b   = (const float*)d_in[7];
    const float* e1_w   = (const float*)d_in[8];
    const float* e1_b   = (const float*)d_in[9];
    const float* bn2_g  = (const float*)d_in[10];
    const float* bn2_b  = (const float*)d_in[11];
    const float* e2_w   = (const float*)d_in[12];
    const float* e2_b   = (const float*)d_in[13];
    const float* f1_w   = (const float*)d_in[14];
    const float* f1_b   = (const float*)d_in[15];
    const float* fa_w   = (const float*)d_in[16];
    const float* fa_b   = (const float*)d_in[17];
    const float* bn3_g  = (const float*)d_in[18];
    const float* bn3_b  = (const float*)d_in[19];
    const float* f2_w   = (const float*)d_in[20];
    const float* f2_b   = (const float*)d_in[21];
    const float* w1     = (const float*)d_in[22];
    const float* b1     = (const float*)d_in[23];
    const float* w2     = (const float*)d_in[24];
    const float* b2     = (const float*)d_in[25];
    const float* w3     = (const float*)d_in[26];
    const float* b3     = (const float*)d_in[27];
    const float* w4     = (const float*)d_in[28];
    const float* b4     = (const float*)d_in[29];
    float* out = (float*)d_out;

    char* w = (char*)d_ws;
    double* bn_d    = (double*)(w + 256);      // 128 dbl
    float* g18      = (float*)(w + 1536);
    float* a1d1     = (float*)(w + 3840);
    float* p1       = (float*)(w + 8192);                 // 4,063,232
    float* p2       = (float*)(w + 4071424);              // 4,063,232
    ushort* wt1     = (ushort*)(w + 13115392);            // 1,572,864
    ushort* wt2     = (ushort*)(w + 14688256);            // 1,048,576
    ushort* wt3     = (ushort*)(w + 15736832);            // 131,072
    double* xp      = (double*)(w + 15867904);            // 139,264 -> 16,007,168

    leaf_kernel<<<2368, 256, 0, stream>>>(x, xp, w1, w2, w3, wt1, wt2, wt3);
    prep_kernel<<<1, 512, 0, stream>>>(xp, la_a, la_b, bn1_g, bn1_b, g18, a1d1);
    branches_kernel<<<2048, 256, 0, stream>>>(
        x, g18, a1d1, a1_w, a1_b, e1_w, e1_b, f1_w, f1_b, fa_w, fa_b, p1, p2);
    pstats_kernel<<<64, 256, 0, stream>>>(p1, p2, bn_d);
    megafc_kernel<<<64, 1024, 0, stream>>>(
        p1, p2, e2_w, e2_b, f2_w, f2_b, bn_d, bn2_g, bn2_b, bn3_g, bn3_b,
        wt1, b1, wt2, b2, wt3, b3, w4, b4, out);
}

// Round 12
// 218.114 us; speedup vs baseline: 1.2083x; 1.2083x over previous
//
#include <hip/hip_runtime.h>
#include <math.h>

// ---------------------------------------------------------------------------
// Sparse_Attn_Logic — round 12: REVERT to R10 (best measured, 220.4us).
// R11 post-mortem: megaFC fusion regressed to 263.5us — 64 blocks on 256 CUs
// (M/16 strip caps the grid), 89.6KB LDS -> 1 block/CU, phase-1 serial loop;
// MfmaUtil 1.1%, occupancy 10.6%. Fused kernels inherit the WORST phase's
// parallelism. Also: R7->R8 (14->10 nodes, -2.4us) and R9->R10 (10->8,
// -2.2us) prove launch overhead ~1us/node, not 10 — node-count surgery is
// exhausted. Remaining time = ~45us harness ws-repoison/restore (fixed) +
// 8 kernels each <41us with all known bottlenecks removed.
// ---------------------------------------------------------------------------

#define L_MP 31

using s8v = __attribute__((ext_vector_type(8))) short;   // 8 bf16 = 4 VGPRs
using f4v = __attribute__((ext_vector_type(4))) float;   // MFMA acc

__device__ __forceinline__ ushort f2bf(float f) {        // RNE fp32->bf16
    unsigned u = __float_as_uint(f);
    u += 0x7fffu + ((u >> 16) & 1u);
    return (ushort)(u >> 16);
}
__device__ __forceinline__ float bf2f(ushort u) {
    return __uint_as_float(((unsigned)u) << 16);
}

// ---------------- K1: x-stats partials  ∪  weight transpose ---------------
__global__ __launch_bounds__(256) void leaf_kernel(
    const float* __restrict__ x, double* __restrict__ xp,
    const float* __restrict__ w1, const float* __restrict__ w2,
    const float* __restrict__ w3,
    ushort* __restrict__ wt1, ushort* __restrict__ wt2, ushort* __restrict__ wt3)
{
    __shared__ __align__(16) float xr[1040];
    __shared__ float wred[4][17];
    __shared__ float tile[32][33];
    int bx = blockIdx.x, tid = threadIdx.x;

    if (bx < 1024) {
        int b = bx;
        for (int i = tid; i < 1024; i += 256) xr[i] = x[b * 1024 + i];
        if (tid < 16) xr[1024 + tid] = 0.f;
        __syncthreads();
        float acc[17];
#pragma unroll
        for (int d = 0; d < 17; ++d) acc[d] = 0.f;
        for (int p = tid; p < 1024; p += 256) {
            float v = xr[p];
            acc[16] += v;
#pragma unroll
            for (int d = 0; d < 16; ++d)
                acc[d] += v * xr[p + d];
        }
#pragma unroll
        for (int off = 32; off >= 1; off >>= 1)
#pragma unroll
            for (int d = 0; d < 17; ++d)
                acc[d] += __shfl_down(acc[d], off);
        int wave = tid >> 6, lane = tid & 63;
        if (lane == 0)
            for (int d = 0; d < 17; ++d) wred[wave][d] = acc[d];
        __syncthreads();
        if (tid < 17) {
            double tot = (double)wred[0][tid] + (double)wred[1][tid]
                       + (double)wred[2][tid] + (double)wred[3][tid];
            xp[tid * 1024 + b] = tot;
        }
    } else {
        int t2 = bx - 1024;
        const float* W; ushort* Wt; int K, N, ntx, tl;
        if (t2 < 768)       { W = w1; Wt = wt1; K = 768;  N = 1024; ntx = 32; tl = t2; }
        else if (t2 < 1280) { W = w2; Wt = wt2; K = 1024; N = 512;  ntx = 16; tl = t2 - 768; }
        else                { W = w3; Wt = wt3; K = 512;  N = 128;  ntx = 4;  tl = t2 - 1280; }
        int n0 = (tl % ntx) * 32, k0 = (tl / ntx) * 32;
        int tx = tid & 31, ty = tid >> 5;
#pragma unroll
        for (int i = 0; i < 4; ++i)
            tile[ty + 8 * i][tx] = W[(size_t)(k0 + ty + 8 * i) * N + n0 + tx];
        __syncthreads();
#pragma unroll
        for (int i = 0; i < 4; ++i)
            Wt[(size_t)(n0 + ty + 8 * i) * K + k0 + tx] = f2bf(tile[tx][ty + 8 * i]);
    }
}

// ---------------- K2: reduce xp + filters + analytic BN1 ------------------
__global__ __launch_bounds__(512) void prep_kernel(
    const double* __restrict__ xp,
    const float* __restrict__ la_a, const float* __restrict__ la_b,
    const float* __restrict__ bn1_g, const float* __restrict__ bn1_b,
    float* __restrict__ g18_out, float* __restrict__ a1d1_out)
{
    __shared__ double stats[17];
    __shared__ float fs[32][16];
    int tid = threadIdx.x, wv = tid >> 6, lane = tid & 63;

    for (int row = wv; row < 17; row += 8) {
        const double* r = xp + (size_t)row * 1024;
        double a = 0.0;
        for (int i = lane; i < 1024; i += 64) a += r[i];
#pragma unroll
        for (int off = 32; off >= 1; off >>= 1) a += __shfl_down(a, off);
        if (lane == 0) stats[row] = a;
    }

    {
        int c = tid >> 4, k = tid & 15;
        const double A = 0.08, ep = 0.03, tal = 0.1;
        const double w = 2.0 * 3.14159265358979323846 * 50.0;
        const double q = 1.0 - ep * ep;
        double t = (double)k / 15.0;
        double p = t - (double)la_b[c] / (double)la_a[c];
        double arg = w * (p - tal);
        double y = A * exp(-ep / sqrt(q) * arg) * (-sin(arg));
        fs[c][k] = (float)y;
    }
    __syncthreads();
    if (tid < 32) {
        int c = tid;
        for (int i = 0; i < 18; ++i) {
            float g = 0.f;
            for (int k = i - 2; k <= i; ++k)
                if (k >= 0 && k < 16) g += fs[c][k];
            g18_out[c * 18 + i] = g;
        }
        double Sf = 0.0;
        for (int k = 0; k < 16; ++k) Sf += (double)fs[c][k];
        double E2 = 0.0;
        for (int k = 0; k < 16; ++k)
            for (int k2 = 0; k2 < 16; ++k2)
                E2 += (double)fs[c][k] * (double)fs[c][k2]
                    * stats[k > k2 ? k - k2 : k2 - k];
        const double N = 1024.0 * 1041.0;
        double Sx = stats[16];
        double mc  = Sx * Sf / N;
        double var = E2 / N - mc * mc;
        double invstd = 1.0 / sqrt(var + 1e-5);
        float alpha = bn1_g[c] * (float)invstd;
        a1d1_out[c]      = alpha / 3.0f;
        a1d1_out[32 + c] = bn1_b[c] - (float)mc * alpha;
    }
}

// ---------------- K3: fused conv+BN+pool + both branches ------------------
__global__ __launch_bounds__(256) void branches_kernel(
    const float* __restrict__ x,
    const float* __restrict__ g18g, const float* __restrict__ a1d1,
    const float* __restrict__ a1w_g, const float* __restrict__ a1b_g,
    const float* __restrict__ e1w_g, const float* __restrict__ e1b_g,
    const float* __restrict__ f1w_g, const float* __restrict__ f1b_g,
    const float* __restrict__ faw_g, const float* __restrict__ fab_g,
    float* __restrict__ p1, float* __restrict__ p2)
{
    __shared__ float xs[1140];            // swizzled x, P(i)=i+(i>>4)
    __shared__ float htail[16][6];

    int blk = blockIdx.x;
    int b = blk >> 1, hf = blk & 1;
    int t = threadIdx.x;
    int wv = t >> 6, lane = t & 63;

    {
        float4 v = ((const float4*)(x + (size_t)b * 1024))[t];
        int li = 16 + 4 * t;
        int ph = li + (li >> 4);
        xs[ph] = v.x; xs[ph + 1] = v.y; xs[ph + 2] = v.z; xs[ph + 3] = v.w;
        if (t < 16) xs[t] = 0.f;
        if (t < 32) { int i = 1040 + t; xs[i + (i >> 4)] = 0.f; }
    }
    __syncthreads();

    if (t < 96) {
        int cl = t / 6, e = t - 6 * (t / 6);
        int cg = hf * 16 + cl;
        float s = 0.f;
#pragma unroll
        for (int i = 0; i < 18; ++i) {
            int li = 1024 + 2 * e + i;
            s += g18g[cg * 18 + i] * xs[li + (li >> 4)];
        }
        htail[cl][e] = s * a1d1[cg] + a1d1[32 + cg];
    }
    __syncthreads();

    float xw[32];
    {
        int base = 17 * lane;
#pragma unroll
        for (int q = 0; q < 16; ++q) xw[q] = xs[base + q];
#pragma unroll
        for (int q = 0; q < 16; ++q) xw[16 + q] = xs[base + 17 + q];
    }

    for (int cc = 0; cc < 4; ++cc) {
        int cl = wv * 4 + cc;
        int cg = __builtin_amdgcn_readfirstlane(hf * 16 + cl);  // SGPR index
        float alpha = a1d1[cg], delta = a1d1[32 + cg];

        float hv[8];
        {
            float g[18];
#pragma unroll
            for (int i = 0; i < 18; ++i) g[i] = g18g[cg * 18 + i];
#pragma unroll
            for (int jj = 0; jj < 8; ++jj) {
                float s = 0.f;
#pragma unroll
                for (int i = 0; i < 18; ++i) s += g[i] * xw[2 * jj + i];
                hv[jj] = s * alpha + delta;
            }
        }

        float x1v[4], x2v[4];
        {
            float hx[14];
#pragma unroll
            for (int q = 0; q < 8; ++q) hx[q] = hv[q];
#pragma unroll
            for (int q = 0; q < 6; ++q) {
                float u = __shfl_down(hv[q], 1);
                float tl = htail[cl][q];
                hx[8 + q] = (lane == 63) ? tl : u;
            }
            float wa[8], wf[8];
            float A1 = a1b_g[cg], F1 = 1.f - f1b_g[cg];
#pragma unroll
            for (int k = 0; k < 8; ++k) {
                wa[k] = a1w_g[cg * 8 + k];
                wf[k] = f1w_g[cg * 8 + k];
                A1 -= wa[k];
            }
#pragma unroll
            for (int nn = 0; nn < 4; ++nn) {
                float s1 = A1, s2 = F1;
#pragma unroll
                for (int k = 0; k < 8; ++k) {
                    float h = hx[2 * nn + k];
                    s1 += h * wa[k];
                    s2 += h * wf[k];
                }
                x1v[nn] = s1 > 0.f ? s1 : 0.f;
                x2v[nn] = s2 > 0.f ? s2 : 0.f;
            }
        }

        float y1v[2], y2v[2];
        {
            float xx1[10], xx2[10];
#pragma unroll
            for (int q = 0; q < 4; ++q) { xx1[q] = x1v[q]; xx2[q] = x2v[q]; }
#pragma unroll
            for (int q = 0; q < 4; ++q) {
                xx1[4 + q] = __shfl_down(x1v[q], 1);
                xx2[4 + q] = __shfl_down(x2v[q], 1);
            }
#pragma unroll
            for (int q = 0; q < 2; ++q) {
                xx1[8 + q] = __shfl_down(x1v[q], 2);
                xx2[8 + q] = __shfl_down(x2v[q], 2);
            }
            float we[8], wfa[8];
            float E1 = 1.f - e1b_g[cg], FA = fab_g[cg];
#pragma unroll
            for (int k = 0; k < 8; ++k) {
                we[k]  = e1w_g[cg * 8 + k];
                wfa[k] = faw_g[cg * 8 + k];
                FA -= wfa[k];
            }
#pragma unroll
            for (int mm = 0; mm < 2; ++mm) {
                float s1 = E1, s2 = FA;
#pragma unroll
                for (int k = 0; k < 8; ++k) {
                    s1 += xx1[2 * mm + k] * we[k];
                    s2 += xx2[2 * mm + k] * wfa[k];
                }
                y1v[mm] = s1 > 0.f ? s1 : 0.f;
                y2v[mm] = s2 > 0.f ? s2 : 0.f;
            }
        }

        {
            float m1 = fmaxf(y1v[0], y1v[1]);
            float m2 = fmaxf(y2v[0], y2v[1]);
            float n1 = __shfl_down(m1, 1);
            float n2 = __shfl_down(m2, 1);
            int tt = lane >> 1;
            if (!(lane & 1) && tt < L_MP) {
                int bc = b * 32 + hf * 16 + cl;
                p1[(size_t)bc * L_MP + tt] = fmaxf(m1, n1);
                p2[(size_t)bc * L_MP + tt] = fmaxf(m2, n2);
            }
        }
    }
}

// ---------------- K3b: BN2/3 stats from p1/p2 (64 blocks) -----------------
__global__ __launch_bounds__(256) void pstats_kernel(
    const float* __restrict__ p1, const float* __restrict__ p2,
    double* __restrict__ bn_d)
{
    __shared__ double wr[4][2];
    int bx = blockIdx.x, arr = bx >> 5, c = bx & 31;
    const float* p = arr ? p2 : p1;
    int t = threadIdx.x, wv = t >> 6, lane = t & 63;
    double s = 0.0, q = 0.0;
    for (int bb = t; bb < 1024; bb += 256) {
        const float* r = p + ((size_t)bb * 32 + c) * L_MP;
#pragma unroll
        for (int j = 0; j < L_MP; ++j) {
            double v = (double)r[j];
            s += v; q += v * v;
        }
    }
#pragma unroll
    for (int off = 32; off >= 1; off >>= 1) {
        s += __shfl_down(s, off);
        q += __shfl_down(q, off);
    }
    if (lane == 0) { wr[wv][0] = s; wr[wv][1] = q; }
    __syncthreads();
    if (t == 0) {
        bn_d[arr * 64 + c]      = wr[0][0] + wr[1][0] + wr[2][0] + wr[3][0];
        bn_d[arr * 64 + 32 + c] = wr[0][1] + wr[1][1] + wr[2][1] + wr[3][1];
    }
}

// ---------------- K5: BN finalize + apply + last Eventually + concat ------
__global__ __launch_bounds__(256) void final_ev_kernel(
    const float* __restrict__ p1, const float* __restrict__ p2,
    const float* __restrict__ e2w_g, const float* __restrict__ e2b_g,
    const float* __restrict__ f2w_g, const float* __restrict__ f2b_g,
    const double* __restrict__ bn_d,
    const float* __restrict__ bn2_g, const float* __restrict__ bn2_b,
    const float* __restrict__ bn3_g, const float* __restrict__ bn3_b,
    ushort* __restrict__ z0)
{
    __shared__ float pr[2][32][31];
    __shared__ float w2s[2][32][8];
    __shared__ float al[2][32], de[2][32], eb[2][32];
    int b = blockIdx.x, tid = threadIdx.x;
    for (int i = tid; i < 992; i += 256) {
        pr[0][0][i] = p1[b * 992 + i];
        pr[1][0][i] = p2[b * 992 + i];
    }
    {
        w2s[0][0][tid] = e2w_g[tid];
        w2s[1][0][tid] = f2w_g[tid];
    }
    if (tid < 64) {
        int br = tid >> 5, c = tid & 31;
        double sum = bn_d[br * 64 + c], sq = bn_d[br * 64 + 32 + c];
        const double N = 1024.0 * 31.0;
        double mean = sum / N;
        double var = sq / N - mean * mean;
        float g  = br ? bn3_g[c] : bn2_g[c];
        float be = br ? bn3_b[c] : bn2_b[c];
        float alpha = g * (float)(1.0 / sqrt(var + 1e-5));
        al[br][c] = alpha;
        de[br][c] = be - (float)mean * alpha;
        eb[br][c] = br ? f2b_g[c] : e2b_g[c];
    }
    __syncthreads();
    for (int u = tid; u < 768; u += 256) {
        int br = u / 384, rem = u - br * 384;
        int c = rem / 12, tt = rem - c * 12;
        float a = al[br][c], d = de[br][c];
        float s = 1.f - eb[br][c];
#pragma unroll
        for (int k = 0; k < 8; ++k)
            s += (pr[br][c][2 * tt + k] * a + d) * w2s[br][c][k];
        z0[(size_t)b * 768 + u] = f2bf(s > 0.f ? s : 0.f);
    }
}

// ---------------- bf16 MFMA GEMM: C = relu(A @ Bt^T + bias), bf16 out -----
template<int NT>
__global__ __launch_bounds__(256) void gemm_mfma_kernel(
    const ushort* __restrict__ A, const ushort* __restrict__ Bt,
    const float* __restrict__ bias, ushort* __restrict__ C,
    int N, int K)
{
    int w = blockIdx.x * 4 + (threadIdx.x >> 6);
    int lane = threadIdx.x & 63;
    int nstr = N / (16 * NT);
    int mt = w / nstr, ns = w - mt * nstr;
    int r = lane & 15, q = lane >> 4;
    const ushort* ap = A + (size_t)(mt * 16 + r) * K + q * 8;
    const ushort* bp[NT];
    f4v acc[NT];
#pragma unroll
    for (int u = 0; u < NT; ++u) {
        bp[u] = Bt + (size_t)(ns * 16 * NT + u * 16 + r) * K + q * 8;
        acc[u] = (f4v){0.f, 0.f, 0.f, 0.f};
    }
    int nk = K >> 5;
    s8v a0 = *(const s8v*)ap;
    s8v b0[NT];
#pragma unroll
    for (int u = 0; u < NT; ++u) b0[u] = *(const s8v*)bp[u];
#pragma unroll 4
    for (int i = 0; i < nk; ++i) {
        int j = (i + 1 < nk) ? i + 1 : i;
        s8v a1 = *(const s8v*)(ap + (size_t)j * 32);
        s8v b1[NT];
#pragma unroll
        for (int u = 0; u < NT; ++u) b1[u] = *(const s8v*)(bp[u] + (size_t)j * 32);
#pragma unroll
        for (int u = 0; u < NT; ++u)
            acc[u] = __builtin_amdgcn_mfma_f32_16x16x32_bf16(a0, b0[u], acc[u], 0, 0, 0);
        a0 = a1;
#pragma unroll
        for (int u = 0; u < NT; ++u) b0[u] = b1[u];
    }
    int row0 = mt * 16 + q * 4;
#pragma unroll
    for (int u = 0; u < NT; ++u) {
        int col = ns * 16 * NT + u * 16 + r;
        float bv = bias[col];
#pragma unroll
        for (int rr = 0; rr < 4; ++rr) {
            float v = acc[u][rr] + bv;
            v = v > 0.f ? v : 0.f;
            C[(size_t)(row0 + rr) * N + col] = f2bf(v);
        }
    }
}

// ---------------- K8: gemm3 + fc4 fused -----------------------------------
__global__ __launch_bounds__(256) void gemm3_fc4_kernel(
    const ushort* __restrict__ A, const ushort* __restrict__ Bt,
    const float* __restrict__ bias, const float* __restrict__ w4,
    const float* __restrict__ b4, float* __restrict__ out)
{
    __shared__ ushort strip[16][132];
    const int K = 512, NCOL = 128;
    int blk = blockIdx.x;
    int wv = threadIdx.x >> 6, lane = threadIdx.x & 63;
    int r = lane & 15, q = lane >> 4;

    const ushort* ap  = A + (size_t)(blk * 16 + r) * K + q * 8;
    const ushort* bp0 = Bt + (size_t)(wv * 32 + r) * K + q * 8;
    const ushort* bp1 = Bt + (size_t)(wv * 32 + 16 + r) * K + q * 8;
    f4v acc0 = {0.f, 0.f, 0.f, 0.f}, acc1 = {0.f, 0.f, 0.f, 0.f};
    int nk = K >> 5;                                   // 16
    s8v a0 = *(const s8v*)ap;
    s8v c0 = *(const s8v*)bp0;
    s8v d0 = *(const s8v*)bp1;
#pragma unroll 4
    for (int i = 0; i < nk; ++i) {
        int j = (i + 1 < nk) ? i + 1 : i;
        s8v a1 = *(const s8v*)(ap + (size_t)j * 32);
        s8v c1 = *(const s8v*)(bp0 + (size_t)j * 32);
        s8v d1 = *(const s8v*)(bp1 + (size_t)j * 32);
        acc0 = __builtin_amdgcn_mfma_f32_16x16x32_bf16(a0, c0, acc0, 0, 0, 0);
        acc1 = __builtin_amdgcn_mfma_f32_16x16x32_bf16(a0, d0, acc1, 0, 0, 0);
        a0 = a1; c0 = c1; d0 = d1;
    }
    float bv0 = bias[wv * 32 + r], bv1 = bias[wv * 32 + 16 + r];
#pragma unroll
    for (int rr = 0; rr < 4; ++rr) {
        float v0 = acc0[rr] + bv0; v0 = v0 > 0.f ? v0 : 0.f;
        float v1 = acc1[rr] + bv1; v1 = v1 > 0.f ? v1 : 0.f;
        strip[q * 4 + rr][wv * 32 + r]      = f2bf(v0);
        strip[q * 4 + rr][wv * 32 + 16 + r] = f2bf(v1);
    }
    __syncthreads();

    int t = threadIdx.x;
    if (t < 160) {
        int m = t / 10, n = t - 10 * (t / 10);
        float a = b4[n];
#pragma unroll 8
        for (int k = 0; k < NCOL; ++k)
            a += bf2f(strip[m][k]) * w4[k * 10 + n];
        out[(size_t)(blk * 16 + m) * 10 + n] = a > 0.f ? a : 0.f;
    }
}

// ---------------------------------------------------------------------------
extern "C" void kernel_launch(void* const* d_in, const int* in_sizes, int n_in,
                              void* d_out, int out_size, void* d_ws, size_t ws_size,
                              hipStream_t stream)
{
    (void)in_sizes; (void)n_in; (void)out_size; (void)ws_size;
    const float* x      = (const float*)d_in[0];
    const float* la_a   = (const float*)d_in[1];
    const float* la_b   = (const float*)d_in[2];
    const float* bn1_g  = (const float*)d_in[4];
    const float* bn1_b  = (const float*)d_in[5];
    const float* a1_w   = (const float*)d_in[6];
    const float* a1_b   = (const float*)d_in[7];
    const float* e1_w   = (const float*)d_in[8];
    const float* e1_b   = (const float*)d_in[9];
    const float* bn2_g  = (const float*)d_in[10];
    const float* bn2_b  = (const float*)d_in[11];
    const float* e2_w   = (const float*)d_in[12];
    const float* e2_b   = (const float*)d_in[13];
    const float* f1_w   = (const float*)d_in[14];
    const float* f1_b   = (const float*)d_in[15];
    const float* fa_w   = (const float*)d_in[16];
    const float* fa_b   = (const float*)d_in[17];
    const float* bn3_g  = (const float*)d_in[18];
    const float* bn3_b  = (const float*)d_in[19];
    const float* f2_w   = (const float*)d_in[20];
    const float* f2_b   = (const float*)d_in[21];
    const float* w1     = (const float*)d_in[22];
    const float* b1     = (const float*)d_in[23];
    const float* w2     = (const float*)d_in[24];
    const float* b2     = (const float*)d_in[25];
    const float* w3     = (const float*)d_in[26];
    const float* b3     = (const float*)d_in[27];
    const float* w4     = (const float*)d_in[28];
    const float* b4     = (const float*)d_in[29];
    float* out = (float*)d_out;

    char* w = (char*)d_ws;
    double* bn_d    = (double*)(w + 256);      // 128 dbl
    float* g18      = (float*)(w + 1536);
    float* a1d1     = (float*)(w + 3840);
    float* p1       = (float*)(w + 8192);                 // 4,063,232
    float* p2       = (float*)(w + 4071424);              // 4,063,232
    ushort* z0bf    = (ushort*)(w + 8134656);             // 1,572,864
    ushort* z1bf    = (ushort*)(w + 9707520);             // 2,097,152
    ushort* z2bf    = (ushort*)(w + 11804672);            // 1,048,576
    ushort* wt1     = (ushort*)(w + 13115392);            // 1,572,864
    ushort* wt2     = (ushort*)(w + 14688256);            // 1,048,576
    ushort* wt3     = (ushort*)(w + 15736832);            // 131,072
    double* xp      = (double*)(w + 15867904);            // 139,264 -> 16,007,168

    leaf_kernel<<<2368, 256, 0, stream>>>(x, xp, w1, w2, w3, wt1, wt2, wt3);
    prep_kernel<<<1, 512, 0, stream>>>(xp, la_a, la_b, bn1_g, bn1_b, g18, a1d1);
    branches_kernel<<<2048, 256, 0, stream>>>(
        x, g18, a1d1, a1_w, a1_b, e1_w, e1_b, f1_w, f1_b, fa_w, fa_b, p1, p2);
    pstats_kernel<<<64, 256, 0, stream>>>(p1, p2, bn_d);
    final_ev_kernel<<<1024, 256, 0, stream>>>(
        p1, p2, e2_w, e2_b, f2_w, f2_b, bn_d, bn2_g, bn2_b, bn3_g, bn3_b, z0bf);
    gemm_mfma_kernel<2><<<512, 256, 0, stream>>>(z0bf, wt1, b1, z1bf, 1024, 768);
    gemm_mfma_kernel<1><<<512, 256, 0, stream>>>(z1bf, wt2, b2, z2bf, 512, 1024);
    gemm3_fc4_kernel<<<64, 256, 0, stream>>>(z2bf, wt3, b3, w4, b4, out);
}